// Round 24
// baseline (316.066 us; speedup 1.0000x reference)
//
#include <hip/hip_runtime.h>
#include <hip/hip_bf16.h>

typedef __bf16 bf16_t;
typedef __bf16 bf16x4 __attribute__((ext_vector_type(4)));
typedef __bf16 bf16x8 __attribute__((ext_vector_type(8)));
typedef float f32x4 __attribute__((ext_vector_type(4)));
typedef unsigned long long u64;

#define MFMA16(a, b, c) __builtin_amdgcn_mfma_f32_16x16x32_bf16(a, b, c, 0, 0, 0)

constexpr int B_ = 2, S_ = 2048, DM = 768, H_ = 8, DK = 96;
constexpr size_t OUT_ELEMS = 3145728;  // Output-0 float32 words
constexpr float INV_SCALE = 0.10206207261596575f;  // 1/sqrt(96)
constexpr float NEGINF = -1e9f;

// ws layout (bytes)
constexpr size_t QW_OFF = 0, KW_OFF = 6291456, VT_OFF = 12582912, WT_OFF = 18874368;
constexpr size_t XC_OFF = 23592960, MB_OFF = 29884416;  // ends ~30.9MB

// ---------------- pack mask -> 1 bit/entry (u64 words) ----------------
__global__ __launch_bounds__(256) void pack_mask(const int* __restrict__ mask,
                                                 u64* __restrict__ bits) {
    const int row = blockIdx.x;  // b*2048 + q
    const int tid = threadIdx.x, lane = tid & 63, wv = tid >> 6;
    const int* mrow = mask + (size_t)row * S_;
    u64* brow = bits + (size_t)row * 32;
#pragma unroll
    for (int p = 0; p < 8; ++p) {
        const u64 b = __ballot(mrow[p * 256 + wv * 64 + lane] != 0);
        if (lane == 0) brow[p * 4 + wv] = b;
    }
}

// ---------------- prep: Wt[z][n][k] = W_z[k][n], cast to bf16 ----------------
__global__ __launch_bounds__(256) void prep_w(const float* __restrict__ w0,
                                              const float* __restrict__ w1,
                                              const float* __restrict__ w2,
                                              const float* __restrict__ w3,
                                              bf16_t* __restrict__ wt) {
    __shared__ float tile[32][33];
    const int z = blockIdx.z;
    const float* W = (z == 0) ? w0 : (z == 1) ? w1 : (z == 2) ? w2 : w3;
    bf16_t* out = wt + (size_t)z * DM * DM;
    const int k0 = blockIdx.x * 32, n0 = blockIdx.y * 32;
    const int tx = threadIdx.x & 31, ty = threadIdx.x >> 5;
#pragma unroll
    for (int i = 0; i < 32; i += 8) tile[ty + i][tx] = W[(size_t)(k0 + ty + i) * DM + n0 + tx];
    __syncthreads();
#pragma unroll
    for (int i = 0; i < 32; i += 8) out[(size_t)(n0 + ty + i) * DM + k0 + tx] = (bf16_t)tile[tx][ty + i];
}

// ---------------- GEMM core: 128x128 tile, K=768 ----------------
template <int AMODE>
__device__ __forceinline__ void gemm_core(const void* __restrict__ Aglob,
                                          const bf16_t* __restrict__ Bt,
                                          int gm0, int gn0, f32x4 acc[4][4]) {
    __shared__ bf16_t As[128][40];
    __shared__ bf16_t Bs[128][40];
    const int tid = threadIdx.x, lane = tid & 63, wid = tid >> 6;
    const int wr = wid >> 1, wc = wid & 1;
    const int l15 = lane & 15, lq = lane >> 4;
    for (int kt = 0; kt < DM / 32; ++kt) {
        if (AMODE == 0) {
            const float* A = (const float*)Aglob;
#pragma unroll
            for (int p = 0; p < 4; ++p) {
                const int row = p * 32 + (tid >> 3);
                const int c4 = (tid & 7) * 4;
                const float4 vv = *(const float4*)&A[(size_t)(gm0 + row) * DM + kt * 32 + c4];
                As[row][c4 + 0] = (bf16_t)vv.x; As[row][c4 + 1] = (bf16_t)vv.y;
                As[row][c4 + 2] = (bf16_t)vv.z; As[row][c4 + 3] = (bf16_t)vv.w;
            }
        } else {
            const bf16_t* A = (const bf16_t*)Aglob;
#pragma unroll
            for (int p = 0; p < 2; ++p) {
                const int row = p * 64 + (tid >> 2);
                const int c8 = (tid & 3) * 8;
                *(uint4*)&As[row][c8] = *(const uint4*)&A[(size_t)(gm0 + row) * DM + kt * 32 + c8];
            }
        }
#pragma unroll
        for (int p = 0; p < 2; ++p) {
            const int row = p * 64 + (tid >> 2);
            const int c8 = (tid & 3) * 8;
            *(uint4*)&Bs[row][c8] = *(const uint4*)&Bt[(size_t)(gn0 + row) * DM + kt * 32 + c8];
        }
        __syncthreads();
        bf16x8 af[4], bfr[4];
#pragma unroll
        for (int i = 0; i < 4; ++i) af[i] = *(const bf16x8*)&As[wr * 64 + i * 16 + l15][lq * 8];
#pragma unroll
        for (int i = 0; i < 4; ++i) bfr[i] = *(const bf16x8*)&Bs[wc * 64 + i * 16 + l15][lq * 8];
#pragma unroll
        for (int i = 0; i < 4; ++i)
#pragma unroll
            for (int j = 0; j < 4; ++j) acc[i][j] = MFMA16(af[i], bfr[j], acc[i][j]);
        __syncthreads();
    }
}

// ---------------- K1: QKV projections (V written transposed) ----------------
__global__ __launch_bounds__(256) void qkv_gemm(const float* __restrict__ Xq,
                                                const float* __restrict__ Xk,
                                                const float* __restrict__ Xv,
                                                const bf16_t* __restrict__ Wt,
                                                bf16_t* __restrict__ Qw,
                                                bf16_t* __restrict__ Kw,
                                                bf16_t* __restrict__ Vt) {
    const int z = blockIdx.z;
    const float* A = (z == 0) ? Xq : (z == 1) ? Xk : Xv;
    const bf16_t* Bz = Wt + (size_t)z * DM * DM;
    const int gm0 = blockIdx.x * 128, gn0 = blockIdx.y * 128;
    f32x4 acc[4][4];
#pragma unroll
    for (int i = 0; i < 4; ++i)
#pragma unroll
        for (int j = 0; j < 4; ++j) acc[i][j] = (f32x4){0.f, 0.f, 0.f, 0.f};
    gemm_core<0>(A, Bz, gm0, gn0, acc);
    const int lane = threadIdx.x & 63, wid = threadIdx.x >> 6;
    const int wr = wid >> 1, wc = wid & 1;
#pragma unroll
    for (int i = 0; i < 4; ++i)
#pragma unroll
        for (int j = 0; j < 4; ++j)
#pragma unroll
            for (int e = 0; e < 4; ++e) {
                const int gm = gm0 + wr * 64 + i * 16 + (lane >> 4) * 4 + e;
                const int gn = gn0 + wc * 64 + j * 16 + (lane & 15);
                const int b = gm >> 11, s = gm & 2047;
                const int h = gn / DK, dk = gn % DK;
                const float val = acc[i][j][e];
                if (z == 2)
                    Vt[(((size_t)b * H_ + h) * DK + dk) * S_ + s] = (bf16_t)val;
                else {
                    bf16_t* dst = (z == 0) ? Qw : Kw;
                    dst[(((size_t)b * H_ + h) * S_ + s) * DK + dk] = (bf16_t)val;
                }
            }
}

// ---------------- K2: fused attn, two-pass online softmax + PV ----------------
// Per wave: 32 q-rows (2 MFMA tiles sharing K/V fragments) x full S.
// Pass 1: swapped QK^T, online (m,s) per row -- logits NOT stored.
// Pass 2: recompute QK^T (bit-identical), p = exp(lv-m)/s, store attn + PV.
__global__ __launch_bounds__(256, 4) void attn_fused(const bf16_t* __restrict__ Qw,
                                                     const bf16_t* __restrict__ Kw,
                                                     const u64* __restrict__ mbits,
                                                     const bf16_t* __restrict__ Vt,
                                                     float* __restrict__ attnf,
                                                     bf16_t* __restrict__ Xc) {
    const int bh = blockIdx.y;
    const int tid = threadIdx.x, lane = tid & 63, w = tid >> 6;
    const int l15 = lane & 15, lq = lane >> 4;
    const int b = bh >> 3, h = bh & 7;
    const int qb = blockIdx.x * 128 + w * 32;  // wave's 32 q-rows

    __shared__ bf16_t p_lds[4][2][16][40];

    // Q fragments (B operand), 2 tiles
    bf16x8 aq0[3], aq1[3];
    {
        const bf16_t* qb0 = Qw + ((size_t)bh * S_ + qb + l15) * DK + lq * 8;
        const bf16_t* qb1 = qb0 + (size_t)16 * DK;
#pragma unroll
        for (int kk = 0; kk < 3; ++kk) {
            aq0[kk] = *(const bf16x8*)(qb0 + kk * 32);
            aq1[kk] = *(const bf16x8*)(qb1 + kk * 32);
        }
    }
    const bf16_t* kbase = Kw + (size_t)bh * S_ * DK + lq * 8;
    const u64* mb0 = mbits + ((size_t)b * S_ + qb + l15) * 32;
    const u64* mb1 = mb0 + 16 * 32;

    // ---- Pass 1: online max/sum ----
    float m0 = -3e38f, s0 = 0.f, m1 = -3e38f, s1 = 0.f;
    for (int tg = 0; tg < 32; ++tg) {
        const u64 w0 = mb0[tg];
        const u64 w1 = mb1[tg];
#pragma unroll
        for (int dt = 0; dt < 4; ++dt) {
            const int t = tg * 4 + dt;
            const bf16_t* kr = kbase + (size_t)(t * 16 + l15) * DK;
            bf16x8 kf0 = *(const bf16x8*)(kr);
            bf16x8 kf1 = *(const bf16x8*)(kr + 32);
            bf16x8 kf2 = *(const bf16x8*)(kr + 64);
            f32x4 a0 = {0.f, 0.f, 0.f, 0.f}, a1 = {0.f, 0.f, 0.f, 0.f};
            a0 = MFMA16(kf0, aq0[0], a0); a0 = MFMA16(kf1, aq0[1], a0); a0 = MFMA16(kf2, aq0[2], a0);
            a1 = MFMA16(kf0, aq1[0], a1); a1 = MFMA16(kf1, aq1[1], a1); a1 = MFMA16(kf2, aq1[2], a1);
            const int sh = dt * 16 + lq * 4;
            const unsigned b0 = (unsigned)(w0 >> sh) & 0xFu;
            const unsigned b1 = (unsigned)(w1 >> sh) & 0xFu;
            float lv0[4], lv1[4];
#pragma unroll
            for (int e = 0; e < 4; ++e) {
                lv0[e] = ((b0 >> e) & 1u) ? a0[e] * INV_SCALE : NEGINF;
                lv1[e] = ((b1 >> e) & 1u) ? a1[e] * INV_SCALE : NEGINF;
            }
            const float tm0 = fmaxf(fmaxf(lv0[0], lv0[1]), fmaxf(lv0[2], lv0[3]));
            const float tm1 = fmaxf(fmaxf(lv1[0], lv1[1]), fmaxf(lv1[2], lv1[3]));
            if (tm0 > m0) { s0 *= __expf(m0 - tm0); m0 = tm0; }
            if (tm1 > m1) { s1 *= __expf(m1 - tm1); m1 = tm1; }
#pragma unroll
            for (int e = 0; e < 4; ++e) {
                s0 += __expf(lv0[e] - m0);
                s1 += __expf(lv1[e] - m1);
            }
        }
    }
    // combine across the 4 lq lanes of each row
#pragma unroll
    for (int off = 16; off <= 32; off <<= 1) {
        const float om0 = __shfl_xor(m0, off, 64), os0 = __shfl_xor(s0, off, 64);
        const float om1 = __shfl_xor(m1, off, 64), os1 = __shfl_xor(s1, off, 64);
        const float nm0 = fmaxf(m0, om0), nm1 = fmaxf(m1, om1);
        s0 = s0 * __expf(m0 - nm0) + os0 * __expf(om0 - nm0);
        s1 = s1 * __expf(m1 - nm1) + os1 * __expf(om1 - nm1);
        m0 = nm0; m1 = nm1;
    }
    const float inv0 = 1.0f / s0, inv1 = 1.0f / s1;

    // ---- Pass 2: recompute, normalize, store attn + PV ----
    f32x4 acc60[6], acc61[6];
#pragma unroll
    for (int f = 0; f < 6; ++f) {
        acc60[f] = (f32x4){0.f, 0.f, 0.f, 0.f};
        acc61[f] = (f32x4){0.f, 0.f, 0.f, 0.f};
    }
    float* arow0 = attnf + ((size_t)bh * S_ + qb + l15) * S_;
    float* arow1 = arow0 + (size_t)16 * S_;
    const bf16_t* vbase = Vt + (size_t)bh * DK * S_ + lq * 8;

    for (int ug = 0; ug < 32; ++ug) {
        const u64 w0 = mb0[ug];
        const u64 w1 = mb1[ug];
#pragma unroll
        for (int uh = 0; uh < 2; ++uh) {
            const int u = ug * 2 + uh;
#pragma unroll
            for (int half = 0; half < 2; ++half) {
                const int t = u * 2 + half;
                const bf16_t* kr = kbase + (size_t)(t * 16 + l15) * DK;
                bf16x8 kf0 = *(const bf16x8*)(kr);
                bf16x8 kf1 = *(const bf16x8*)(kr + 32);
                bf16x8 kf2 = *(const bf16x8*)(kr + 64);
                f32x4 a0 = {0.f, 0.f, 0.f, 0.f}, a1 = {0.f, 0.f, 0.f, 0.f};
                a0 = MFMA16(kf0, aq0[0], a0); a0 = MFMA16(kf1, aq0[1], a0); a0 = MFMA16(kf2, aq0[2], a0);
                a1 = MFMA16(kf0, aq1[0], a1); a1 = MFMA16(kf1, aq1[1], a1); a1 = MFMA16(kf2, aq1[2], a1);
                const int sh = (uh * 2 + half) * 16 + lq * 4;
                const unsigned b0 = (unsigned)(w0 >> sh) & 0xFu;
                const unsigned b1 = (unsigned)(w1 >> sh) & 0xFu;
                bf16x4 nb0, nb1;
#pragma unroll
                for (int e = 0; e < 4; ++e) {
                    const float lv0 = ((b0 >> e) & 1u) ? a0[e] * INV_SCALE : NEGINF;
                    const float lv1 = ((b1 >> e) & 1u) ? a1[e] * INV_SCALE : NEGINF;
                    nb0[e] = (bf16_t)(__expf(lv0 - m0) * inv0);
                    nb1[e] = (bf16_t)(__expf(lv1 - m1) * inv1);
                }
                float4 st0, st1;
                st0.x = (float)nb0[0]; st0.y = (float)nb0[1]; st0.z = (float)nb0[2]; st0.w = (float)nb0[3];
                st1.x = (float)nb1[0]; st1.y = (float)nb1[1]; st1.z = (float)nb1[2]; st1.w = (float)nb1[3];
                *(float4*)(arow0 + t * 16 + lq * 4) = st0;
                *(float4*)(arow1 + t * 16 + lq * 4) = st1;
                *(bf16x4*)&p_lds[w][0][l15][half * 16 + lq * 4] = nb0;
                *(bf16x4*)&p_lds[w][1][l15][half * 16 + lq * 4] = nb1;
            }
            asm volatile("s_waitcnt lgkmcnt(0)" ::: "memory");
            const bf16x8 pa0 = *(const bf16x8*)&p_lds[w][0][l15][lq * 8];
            const bf16x8 pa1 = *(const bf16x8*)&p_lds[w][1][l15][lq * 8];
            const int k0 = u * 32;
#pragma unroll
            for (int f = 0; f < 6; ++f) {
                const bf16x8 vb = *(const bf16x8*)(vbase + (size_t)(f * 16 + l15) * S_ + k0);
                acc60[f] = MFMA16(pa0, vb, acc60[f]);
                acc61[f] = MFMA16(pa1, vb, acc61[f]);
            }
        }
    }

    // ---- Xc store (per wave, no cross-wave reduction) ----
#pragma unroll
    for (int f = 0; f < 6; ++f)
#pragma unroll
        for (int e = 0; e < 4; ++e) {
            const int col = h * DK + f * 16 + l15;
            const int q0r = qb + lq * 4 + e;
            Xc[((size_t)b * S_ + q0r) * DM + col] = (bf16_t)acc60[f][e];
            Xc[((size_t)b * S_ + q0r + 16) * DM + col] = (bf16_t)acc61[f][e];
        }
}

// ---------------- K4: out = concat @ Wo (float32 out) ----------------
__global__ __launch_bounds__(256) void out_gemm(const bf16_t* __restrict__ Xc,
                                                const bf16_t* __restrict__ Wot,
                                                float* __restrict__ outf) {
    const int gm0 = blockIdx.x * 128, gn0 = blockIdx.y * 128;
    f32x4 acc[4][4];
#pragma unroll
    for (int i = 0; i < 4; ++i)
#pragma unroll
        for (int j = 0; j < 4; ++j) acc[i][j] = (f32x4){0.f, 0.f, 0.f, 0.f};
    gemm_core<1>(Xc, Wot, gm0, gn0, acc);
    const int lane = threadIdx.x & 63, wid = threadIdx.x >> 6;
    const int wr = wid >> 1, wc = wid & 1;
#pragma unroll
    for (int i = 0; i < 4; ++i)
#pragma unroll
        for (int j = 0; j < 4; ++j)
#pragma unroll
            for (int e = 0; e < 4; ++e) {
                const int gm = gm0 + wr * 64 + i * 16 + (lane >> 4) * 4 + e;
                const int gn = gn0 + wc * 64 + j * 16 + (lane & 15);
                outf[(size_t)gm * DM + gn] = (float)(bf16_t)acc[i][j][e];
            }
}

extern "C" void kernel_launch(void* const* d_in, const int* in_sizes, int n_in,
                              void* d_out, int out_size, void* d_ws, size_t ws_size,
                              hipStream_t stream) {
    const float* q = (const float*)d_in[0];
    const float* k = (const float*)d_in[1];
    const float* v = (const float*)d_in[2];
    const int* mask = (const int*)d_in[3];
    const float* Wq = (const float*)d_in[4];
    const float* Wk = (const float*)d_in[5];
    const float* Wv = (const float*)d_in[6];
    const float* Wo = (const float*)d_in[7];

    float* outf = (float*)d_out;               // Output 0
    float* attnf = (float*)d_out + OUT_ELEMS;  // Output 1

    char* ws = (char*)d_ws;
    bf16_t* Qw = (bf16_t*)(ws + QW_OFF);
    bf16_t* Kw = (bf16_t*)(ws + KW_OFF);
    bf16_t* Vt = (bf16_t*)(ws + VT_OFF);
    bf16_t* Wt = (bf16_t*)(ws + WT_OFF);
    bf16_t* Xc = (bf16_t*)(ws + XC_OFF);
    u64* mbits = (u64*)(ws + MB_OFF);

    prep_w<<<dim3(24, 24, 4), 256, 0, stream>>>(Wq, Wk, Wv, Wo, Wt);
    pack_mask<<<B_ * S_, 256, 0, stream>>>(mask, mbits);
    qkv_gemm<<<dim3(32, 6, 3), 256, 0, stream>>>(q, k, v, Wt, Qw, Kw, Vt);
    attn_fused<<<dim3(16, 16), 256, 0, stream>>>(Qw, Kw, mbits, Vt, attnf, Xc);
    out_gemm<<<dim3(32, 6), 256, 0, stream>>>(Xc, Wt + (size_t)3 * DM * DM, outf);
}

// Round 25
// 248.502 us; speedup vs baseline: 1.2719x; 1.2719x over previous
//
#include <hip/hip_runtime.h>
#include <hip/hip_bf16.h>

typedef __bf16 bf16_t;
typedef __bf16 bf16x4 __attribute__((ext_vector_type(4)));
typedef __bf16 bf16x8 __attribute__((ext_vector_type(8)));
typedef float f32x4 __attribute__((ext_vector_type(4)));
typedef unsigned long long u64;

#define MFMA16(a, b, c) __builtin_amdgcn_mfma_f32_16x16x32_bf16(a, b, c, 0, 0, 0)

constexpr int B_ = 2, S_ = 2048, DM = 768, H_ = 8, DK = 96;
constexpr size_t OUT_ELEMS = 3145728;  // Output-0 float32 words
constexpr float INV_SCALE = 0.10206207261596575f;  // 1/sqrt(96)
constexpr float NEGINF = -1e9f;

// ws layout (bytes)
constexpr size_t QW_OFF = 0, KW_OFF = 6291456, VT_OFF = 12582912, WT_OFF = 18874368;
constexpr size_t XC_OFF = 23592960, MB_OFF = 29884416;

// ---------------- pack mask -> 1 bit/entry ----------------
__global__ __launch_bounds__(256) void pack_mask(const int* __restrict__ mask,
                                                 u64* __restrict__ bits) {
    const int row = blockIdx.x;
    const int tid = threadIdx.x, lane = tid & 63, wv = tid >> 6;
    const int* mrow = mask + (size_t)row * S_;
    u64* brow = bits + (size_t)row * 32;
#pragma unroll
    for (int p = 0; p < 8; ++p) {
        const u64 b = __ballot(mrow[p * 256 + wv * 64 + lane] != 0);
        if (lane == 0) brow[p * 4 + wv] = b;
    }
}

// ---------------- prep: Wt[z][n][k] = W_z[k][n] ----------------
__global__ __launch_bounds__(256) void prep_w(const float* __restrict__ w0,
                                              const float* __restrict__ w1,
                                              const float* __restrict__ w2,
                                              const float* __restrict__ w3,
                                              bf16_t* __restrict__ wt) {
    __shared__ float tile[32][33];
    const int z = blockIdx.z;
    const float* W = (z == 0) ? w0 : (z == 1) ? w1 : (z == 2) ? w2 : w3;
    bf16_t* out = wt + (size_t)z * DM * DM;
    const int k0 = blockIdx.x * 32, n0 = blockIdx.y * 32;
    const int tx = threadIdx.x & 31, ty = threadIdx.x >> 5;
#pragma unroll
    for (int i = 0; i < 32; i += 8) tile[ty + i][tx] = W[(size_t)(k0 + ty + i) * DM + n0 + tx];
    __syncthreads();
#pragma unroll
    for (int i = 0; i < 32; i += 8) out[(size_t)(n0 + ty + i) * DM + k0 + tx] = (bf16_t)tile[tx][ty + i];
}

// ---------------- GEMM core: 128x128 tile, K=768 ----------------
template <int AMODE>
__device__ __forceinline__ void gemm_core(const void* __restrict__ Aglob,
                                          const bf16_t* __restrict__ Bt,
                                          int gm0, int gn0, f32x4 acc[4][4]) {
    __shared__ bf16_t As[128][40];
    __shared__ bf16_t Bs[128][40];
    const int tid = threadIdx.x, lane = tid & 63, wid = tid >> 6;
    const int wr = wid >> 1, wc = wid & 1;
    const int l15 = lane & 15, lq = lane >> 4;
    for (int kt = 0; kt < DM / 32; ++kt) {
        if (AMODE == 0) {
            const float* A = (const float*)Aglob;
#pragma unroll
            for (int p = 0; p < 4; ++p) {
                const int row = p * 32 + (tid >> 3);
                const int c4 = (tid & 7) * 4;
                const float4 vv = *(const float4*)&A[(size_t)(gm0 + row) * DM + kt * 32 + c4];
                As[row][c4 + 0] = (bf16_t)vv.x; As[row][c4 + 1] = (bf16_t)vv.y;
                As[row][c4 + 2] = (bf16_t)vv.z; As[row][c4 + 3] = (bf16_t)vv.w;
            }
        } else {
            const bf16_t* A = (const bf16_t*)Aglob;
#pragma unroll
            for (int p = 0; p < 2; ++p) {
                const int row = p * 64 + (tid >> 2);
                const int c8 = (tid & 3) * 8;
                *(uint4*)&As[row][c8] = *(const uint4*)&A[(size_t)(gm0 + row) * DM + kt * 32 + c8];
            }
        }
#pragma unroll
        for (int p = 0; p < 2; ++p) {
            const int row = p * 64 + (tid >> 2);
            const int c8 = (tid & 3) * 8;
            *(uint4*)&Bs[row][c8] = *(const uint4*)&Bt[(size_t)(gn0 + row) * DM + kt * 32 + c8];
        }
        __syncthreads();
        bf16x8 af[4], bfr[4];
#pragma unroll
        for (int i = 0; i < 4; ++i) af[i] = *(const bf16x8*)&As[wr * 64 + i * 16 + l15][lq * 8];
#pragma unroll
        for (int i = 0; i < 4; ++i) bfr[i] = *(const bf16x8*)&Bs[wc * 64 + i * 16 + l15][lq * 8];
#pragma unroll
        for (int i = 0; i < 4; ++i)
#pragma unroll
            for (int j = 0; j < 4; ++j) acc[i][j] = MFMA16(af[i], bfr[j], acc[i][j]);
        __syncthreads();
    }
}

// ---------------- K1: QKV projections (V written transposed) ----------------
__global__ __launch_bounds__(256) void qkv_gemm(const float* __restrict__ Xq,
                                                const float* __restrict__ Xk,
                                                const float* __restrict__ Xv,
                                                const bf16_t* __restrict__ Wt,
                                                bf16_t* __restrict__ Qw,
                                                bf16_t* __restrict__ Kw,
                                                bf16_t* __restrict__ Vt) {
    const int z = blockIdx.z;
    const float* A = (z == 0) ? Xq : (z == 1) ? Xk : Xv;
    const bf16_t* Bz = Wt + (size_t)z * DM * DM;
    const int gm0 = blockIdx.x * 128, gn0 = blockIdx.y * 128;
    f32x4 acc[4][4];
#pragma unroll
    for (int i = 0; i < 4; ++i)
#pragma unroll
        for (int j = 0; j < 4; ++j) acc[i][j] = (f32x4){0.f, 0.f, 0.f, 0.f};
    gemm_core<0>(A, Bz, gm0, gn0, acc);
    const int lane = threadIdx.x & 63, wid = threadIdx.x >> 6;
    const int wr = wid >> 1, wc = wid & 1;
#pragma unroll
    for (int i = 0; i < 4; ++i)
#pragma unroll
        for (int j = 0; j < 4; ++j)
#pragma unroll
            for (int e = 0; e < 4; ++e) {
                const int gm = gm0 + wr * 64 + i * 16 + (lane >> 4) * 4 + e;
                const int gn = gn0 + wc * 64 + j * 16 + (lane & 15);
                const int b = gm >> 11, s = gm & 2047;
                const int h = gn / DK, dk = gn % DK;
                const float val = acc[i][j][e];
                if (z == 2)
                    Vt[(((size_t)b * H_ + h) * DK + dk) * S_ + s] = (bf16_t)val;
                else {
                    bf16_t* dst = (z == 0) ? Qw : Kw;
                    dst[(((size_t)b * H_ + h) * S_ + s) * DK + dk] = (bf16_t)val;
                }
            }
}

// ---------------- K2: fused attn (one-pass, 8 waves x 256-k strips) ----------------
// Block: 512 thr = 8 waves; all waves share the block's 16 q-rows; wave w owns
// k in [w*256, w*256+256) -> accs[16] (64 VGPR). Swapped QK^T (col=q,row=k):
// bit-mask from packed u64, 2-shfl + LDS row reduction, float4 attn stores,
// in-register P -> LDS 8B stage -> PV MFMA; cross-wave PV reduction in LDS.
__global__ __launch_bounds__(512, 4) void attn_fused(const bf16_t* __restrict__ Qw,
                                                     const bf16_t* __restrict__ Kw,
                                                     const u64* __restrict__ mbits,
                                                     const bf16_t* __restrict__ Vt,
                                                     float* __restrict__ attnf,
                                                     bf16_t* __restrict__ Xc) {
    const int bh = blockIdx.y;
    const int q0 = blockIdx.x * 16;
    const int tid = threadIdx.x, lane = tid & 63, w = tid >> 6;
    const int l15 = lane & 15, lq = lane >> 4;
    const int b = bh >> 3, h = bh & 7;

    __shared__ float redmax[8][16];
    __shared__ float redsum[8][16];
    __shared__ bf16_t p_lds[8][16][40];
    __shared__ float pv_part[8][16][96];

    // Q fragments (B operand)
    bf16x8 aq[3];
    {
        const bf16_t* qb = Qw + ((size_t)bh * S_ + q0 + l15) * DK + lq * 8;
#pragma unroll
        for (int kk = 0; kk < 3; ++kk) aq[kk] = *(const bf16x8*)(qb + kk * 32);
    }
    const bf16_t* kbase = Kw + (size_t)bh * S_ * DK + lq * 8;
    const u64* mb = mbits + ((size_t)b * S_ + q0 + l15) * 32;

    // ---- Phase 1: logits (swapped), mask, row max ----
    f32x4 accs[16];
    float rmax = -1e30f;
#pragma unroll
    for (int tg = 0; tg < 4; ++tg) {
        const u64 mw = mb[w * 4 + tg];
#pragma unroll
        for (int dt = 0; dt < 4; ++dt) {
            const int t = tg * 4 + dt;                     // local tile 0..15
            const int kt = w * 16 + t;                     // global k-tile
            const bf16_t* kr = kbase + (size_t)(kt * 16 + l15) * DK;
            f32x4 acc = {0.f, 0.f, 0.f, 0.f};
            acc = MFMA16(*(const bf16x8*)(kr), aq[0], acc);
            acc = MFMA16(*(const bf16x8*)(kr + 32), aq[1], acc);
            acc = MFMA16(*(const bf16x8*)(kr + 64), aq[2], acc);
            const int sh = dt * 16 + lq * 4;
            const unsigned bm = (unsigned)(mw >> sh) & 0xFu;
#pragma unroll
            for (int e = 0; e < 4; ++e) {
                const float lv = ((bm >> e) & 1u) ? acc[e] * INV_SCALE : NEGINF;
                acc[e] = lv;
                rmax = fmaxf(rmax, lv);
            }
            accs[t] = acc;
        }
    }
    rmax = fmaxf(rmax, __shfl_xor(rmax, 16, 64));
    rmax = fmaxf(rmax, __shfl_xor(rmax, 32, 64));
    if (lane < 16) redmax[w][lane] = rmax;
    __syncthreads();
    float gmax = redmax[0][l15];
#pragma unroll
    for (int i = 1; i < 8; ++i) gmax = fmaxf(gmax, redmax[i][l15]);

    // ---- exp + row sum ----
    float rsum = 0.f;
#pragma unroll
    for (int t = 0; t < 16; ++t)
#pragma unroll
        for (int e = 0; e < 4; ++e) {
            const float ev = __expf(accs[t][e] - gmax);
            accs[t][e] = ev;
            rsum += ev;
        }
    rsum += __shfl_xor(rsum, 16, 64);
    rsum += __shfl_xor(rsum, 32, 64);
    if (lane < 16) redsum[w][lane] = rsum;
    __syncthreads();
    float ssum = redsum[0][l15];
#pragma unroll
    for (int i = 1; i < 8; ++i) ssum += redsum[i][l15];
    const float inv = 1.0f / ssum;

    // ---- Phase 2: store normalized attn + PV accumulate ----
    f32x4 acc6[6];
#pragma unroll
    for (int f = 0; f < 6; ++f) acc6[f] = (f32x4){0.f, 0.f, 0.f, 0.f};
    float* arow = attnf + ((size_t)bh * S_ + q0 + l15) * S_ + w * 256;
    const bf16_t* vbase = Vt + (size_t)bh * DK * S_ + lq * 8;

#pragma unroll
    for (int u = 0; u < 8; ++u) {
#pragma unroll
        for (int half = 0; half < 2; ++half) {
            const int t = 2 * u + half;
            bf16x4 nb;
#pragma unroll
            for (int e = 0; e < 4; ++e) nb[e] = (bf16_t)(accs[t][e] * inv);
            float4 st;
            st.x = (float)nb[0]; st.y = (float)nb[1]; st.z = (float)nb[2]; st.w = (float)nb[3];
            *(float4*)(arow + t * 16 + lq * 4) = st;
            *(bf16x4*)&p_lds[w][l15][half * 16 + lq * 4] = nb;
        }
        asm volatile("s_waitcnt lgkmcnt(0)" ::: "memory");
        const bf16x8 pa = *(const bf16x8*)&p_lds[w][l15][lq * 8];
        const int k0 = w * 256 + u * 32;
#pragma unroll
        for (int f = 0; f < 6; ++f) {
            const bf16x8 vb = *(const bf16x8*)(vbase + (size_t)(f * 16 + l15) * S_ + k0);
            acc6[f] = MFMA16(pa, vb, acc6[f]);
        }
    }

    // ---- cross-wave PV reduction + Xc store ----
#pragma unroll
    for (int f = 0; f < 6; ++f)
#pragma unroll
        for (int e = 0; e < 4; ++e) pv_part[w][lq * 4 + e][f * 16 + l15] = acc6[f][e];
    __syncthreads();
    for (int i = tid; i < 16 * 96; i += 512) {
        const int row = i / 96, col = i % 96;
        float s = pv_part[0][row][col];
#pragma unroll
        for (int j = 1; j < 8; ++j) s += pv_part[j][row][col];
        Xc[((size_t)b * S_ + q0 + row) * DM + h * DK + col] = (bf16_t)s;
    }
}

// ---------------- K4: out = concat @ Wo ----------------
__global__ __launch_bounds__(256) void out_gemm(const bf16_t* __restrict__ Xc,
                                                const bf16_t* __restrict__ Wot,
                                                float* __restrict__ outf) {
    const int gm0 = blockIdx.x * 128, gn0 = blockIdx.y * 128;
    f32x4 acc[4][4];
#pragma unroll
    for (int i = 0; i < 4; ++i)
#pragma unroll
        for (int j = 0; j < 4; ++j) acc[i][j] = (f32x4){0.f, 0.f, 0.f, 0.f};
    gemm_core<1>(Xc, Wot, gm0, gn0, acc);
    const int lane = threadIdx.x & 63, wid = threadIdx.x >> 6;
    const int wr = wid >> 1, wc = wid & 1;
#pragma unroll
    for (int i = 0; i < 4; ++i)
#pragma unroll
        for (int j = 0; j < 4; ++j)
#pragma unroll
            for (int e = 0; e < 4; ++e) {
                const int gm = gm0 + wr * 64 + i * 16 + (lane >> 4) * 4 + e;
                const int gn = gn0 + wc * 64 + j * 16 + (lane & 15);
                outf[(size_t)gm * DM + gn] = (float)(bf16_t)acc[i][j][e];
            }
}

extern "C" void kernel_launch(void* const* d_in, const int* in_sizes, int n_in,
                              void* d_out, int out_size, void* d_ws, size_t ws_size,
                              hipStream_t stream) {
    const float* q = (const float*)d_in[0];
    const float* k = (const float*)d_in[1];
    const float* v = (const float*)d_in[2];
    const int* mask = (const int*)d_in[3];
    const float* Wq = (const float*)d_in[4];
    const float* Wk = (const float*)d_in[5];
    const float* Wv = (const float*)d_in[6];
    const float* Wo = (const float*)d_in[7];

    float* outf = (float*)d_out;               // Output 0
    float* attnf = (float*)d_out + OUT_ELEMS;  // Output 1

    char* ws = (char*)d_ws;
    bf16_t* Qw = (bf16_t*)(ws + QW_OFF);
    bf16_t* Kw = (bf16_t*)(ws + KW_OFF);
    bf16_t* Vt = (bf16_t*)(ws + VT_OFF);
    bf16_t* Wt = (bf16_t*)(ws + WT_OFF);
    bf16_t* Xc = (bf16_t*)(ws + XC_OFF);
    u64* mbits = (u64*)(ws + MB_OFF);

    prep_w<<<dim3(24, 24, 4), 256, 0, stream>>>(Wq, Wk, Wv, Wo, Wt);
    pack_mask<<<B_ * S_, 256, 0, stream>>>(mask, mbits);
    qkv_gemm<<<dim3(32, 6, 3), 256, 0, stream>>>(q, k, v, Wt, Qw, Kw, Vt);
    attn_fused<<<dim3(128, 16), 512, 0, stream>>>(Qw, Kw, mbits, Vt, attnf, Xc);
    out_gemm<<<dim3(32, 6), 256, 0, stream>>>(Xc, Wt + (size_t)3 * DM * DM, outf);
}